// Round 4
// baseline (253.119 us; speedup 1.0000x reference)
//
#include <hip/hip_runtime.h>

// Problem constants (from reference): B=8, N=256, F_IN=F_OUT=64, all fp32 I/O.
#define NN    256
#define FF    64
#define BROWS 2048            // B*N
#define W_ELEMS 33554432      // 8*256*256*64

typedef float v4f __attribute__((ext_vector_type(4)));

// ---------------------------------------------------------------------------
// Kernel 1: both MLPs (n_func and s_func) in fp32, outputs to workspace.
// One block (64 threads) per (b,i) row. Weight matrices are 16 KB each and
// L2-resident across all 2048 blocks.  (~1-2 us total; not the bottleneck.)
// ---------------------------------------------------------------------------
__global__ __launch_bounds__(64) void mlp_kernel(
    const float* __restrict__ x,
    const float* __restrict__ nw1, const float* __restrict__ nb1,
    const float* __restrict__ nw2, const float* __restrict__ nb2,
    const float* __restrict__ sw1, const float* __restrict__ sb1,
    const float* __restrict__ sw2, const float* __restrict__ sb2,
    float* __restrict__ x1, float* __restrict__ sout)
{
    const int row = blockIdx.x;      // b*N + i
    const int e   = threadIdx.x;     // 0..63

    __shared__ float xr[FF];
    __shared__ float h[FF];

    xr[e] = x[row * FF + e];
    __syncthreads();

    // n_func layer 1
    float acc = nb1[e];
#pragma unroll
    for (int k = 0; k < FF; ++k) acc = fmaf(xr[k], nw1[k * FF + e], acc);
    h[e] = fmaxf(acc, 0.0f);
    __syncthreads();

    // n_func layer 2
    acc = nb2[e];
#pragma unroll
    for (int k = 0; k < FF; ++k) acc = fmaf(h[k], nw2[k * FF + e], acc);
    x1[row * FF + e] = fmaxf(acc, 0.0f);
    __syncthreads();   // everyone done reading h before overwrite

    // s_func layer 1
    acc = sb1[e];
#pragma unroll
    for (int k = 0; k < FF; ++k) acc = fmaf(xr[k], sw1[k * FF + e], acc);
    h[e] = fmaxf(acc, 0.0f);
    __syncthreads();

    // s_func layer 2
    acc = sb2[e];
#pragma unroll
    for (int k = 0; k < FF; ++k) acc = fmaf(h[k], sw2[k * FF + e], acc);
    sout[row * FF + e] = fmaxf(acc, 0.0f);
}

// ---------------------------------------------------------------------------
// Kernel 2: per (b,i) row — L1-normalize A row, stream the 64 KB W row once:
//   outW = W (passthrough), x2[e] = sum_j An[j]*W[j,e]*x1[b,j,e] + sout[e]
//
// v2.1 (v2 with the token-paste macro bug fixed via register arrays):
//   * depth-2 software pipeline over 4-chunk groups: next group's 8 loads are
//     issued BEFORE current group's stores/FMAs, so the store's vmcnt wait
//     never drains the load queue.
//   * nontemporal W loads + outW stores: 268 MB of zero-reuse stream no
//     longer evicts the L2-resident x1/A working set.
//   * __launch_bounds__(256,4): cap VGPRs at 128 -> no register blowup.
//   * wA/xA arrays are indexed only by fully-unrolled compile-time constants
//     -> stay in VGPRs (no scratch).
// Thread = (jg = tid>>4 handles j in {jj*16+jg}, fc = tid&15 feature quad);
// chunk index ci = jj*256 + tid == j*16 + fc -> perfectly coalesced 16 B/lane,
// and the SAME index addresses x1's float4 for (j, fc).
// ---------------------------------------------------------------------------
__global__ __launch_bounds__(256, 4) void agg_kernel(
    const float* __restrict__ A, const float* __restrict__ W,
    const float* __restrict__ x1, const float* __restrict__ sout,
    float* __restrict__ outW, float* __restrict__ outx2)
{
    const int row = blockIdx.x;      // b*N + i
    const int b   = row >> 8;        // N = 256
    const int tid = threadIdx.x;

    __shared__ float an[NN];
    __shared__ float partial[4];
    __shared__ float red[256][4];

    // ---- L1 row normalization of A ----
    const float a = A[row * NN + tid];
    float s = fabsf(a);
#pragma unroll
    for (int off = 32; off > 0; off >>= 1) s += __shfl_down(s, off, 64);
    if ((tid & 63) == 0) partial[tid >> 6] = s;
    __syncthreads();
    const float denom = fmaxf(partial[0] + partial[1] + partial[2] + partial[3], 1e-12f);
    an[tid] = a / denom;
    __syncthreads();

    // ---- stream W row: copy out + weighted aggregation ----
    const v4f* __restrict__ Wrow = (const v4f*)(W + (size_t)row * (NN * FF));
    v4f* __restrict__ Orow       = (v4f*)(outW + (size_t)row * (NN * FF));
    const v4f* __restrict__ x1b  = (const v4f*)(x1 + b * (NN * FF));

    const int jg = tid >> 4;     // j-subgroup 0..15

    float acc0 = 0.0f, acc1 = 0.0f, acc2 = 0.0f, acc3 = 0.0f;

    // One group = 4 consecutive jj chunks (cbase = jj*256 .. +3*256).
    // All q-indices are compile-time constants after unroll -> registers.
#define LOADG(wp, xp, cbase)                                                  \
    _Pragma("unroll")                                                         \
    for (int q = 0; q < 4; ++q) {                                             \
        wp[q] = __builtin_nontemporal_load(Wrow + (cbase) + q * 256 + tid);   \
        xp[q] = x1b[(cbase) + q * 256 + tid];                                 \
    }

#define USEG(wp, xp, cbase, jjb)                                              \
    _Pragma("unroll")                                                         \
    for (int q = 0; q < 4; ++q) {                                             \
        __builtin_nontemporal_store(wp[q], Orow + (cbase) + q * 256 + tid);   \
    }                                                                         \
    _Pragma("unroll")                                                         \
    for (int q = 0; q < 4; ++q) {                                             \
        const float av = an[((jjb) + q) * 16 + jg];                           \
        acc0 = fmaf(av * wp[q].x, xp[q].x, acc0);                             \
        acc1 = fmaf(av * wp[q].y, xp[q].y, acc1);                             \
        acc2 = fmaf(av * wp[q].z, xp[q].z, acc2);                             \
        acc3 = fmaf(av * wp[q].w, xp[q].w, acc3);                             \
    }

    v4f wA[4], xA[4];
    v4f wB[4], xB[4];

    LOADG(wA, xA, 0)          // group 0: jj 0..3
    LOADG(wB, xB, 1024)       // group 1: jj 4..7   (in flight behind group 0)
    USEG (wA, xA, 0, 0)
    LOADG(wA, xA, 2048)       // group 2: jj 8..11
    USEG (wB, xB, 1024, 4)
    LOADG(wB, xB, 3072)       // group 3: jj 12..15
    USEG (wA, xA, 2048, 8)
    USEG (wB, xB, 3072, 12)

#undef LOADG
#undef USEG

    // ---- reduce over the 16 j-groups ----
    red[tid][0] = acc0; red[tid][1] = acc1;
    red[tid][2] = acc2; red[tid][3] = acc3;
    __syncthreads();

    if (tid < 64) {
        const int c = tid >> 2;      // feature quad
        const int r = tid & 3;       // elem within quad -> feature = c*4+r = tid
        float sum = 0.0f;
#pragma unroll
        for (int g = 0; g < 16; ++g) sum += red[g * 16 + c][r];  // 2-way bank alias, free
        sum += sout[row * FF + tid];
        outx2[row * FF + tid] = sum;
    }
}

extern "C" void kernel_launch(void* const* d_in, const int* in_sizes, int n_in,
                              void* d_out, int out_size, void* d_ws, size_t ws_size,
                              hipStream_t stream) {
    const float* A   = (const float*)d_in[0];
    const float* W   = (const float*)d_in[1];
    const float* x   = (const float*)d_in[2];
    const float* nw1 = (const float*)d_in[3];
    const float* nb1 = (const float*)d_in[4];
    const float* nw2 = (const float*)d_in[5];
    const float* nb2 = (const float*)d_in[6];
    const float* sw1 = (const float*)d_in[7];
    const float* sb1 = (const float*)d_in[8];
    const float* sw2 = (const float*)d_in[9];
    const float* sb2 = (const float*)d_in[10];

    float* x1 = (float*)d_ws;                  // 2048*64 fp32 = 512 KB
    float* so = x1 + BROWS * FF;               // + 512 KB

    float* outW  = (float*)d_out;
    float* outx2 = outW + W_ELEMS;

    mlp_kernel<<<BROWS, 64, 0, stream>>>(x, nw1, nb1, nw2, nb2,
                                         sw1, sb1, sw2, sb2, x1, so);
    agg_kernel<<<BROWS, 256, 0, stream>>>(A, W, x1, so, outW, outx2);
}